// Round 2
// baseline (894.228 us; speedup 1.0000x reference)
//
#include <hip/hip_runtime.h>
#include <stdint.h>

// ---------------------------------------------------------------------------
// GNNWithMoE: 2x GGNN(edge-embed + scatter-add + GRU) -> soft MoE -> mean pool
// ALL float tensors are fp32 (per reference file); ints are int32; out fp32.
// MFMA GEMMs run in bf16 (inputs converted in-kernel, weights pre-converted).
// Workspace layout (d_ws):
//   m    : N*64 fp32 message accumulator (12.8 MB)
//   h    : N*64 fp32 hidden             (12.8 MB)
//   pool : B*64 fp32 + cnt B fp32
//   wbf  : bf16 weights [w_ih1|w_hh1|w_ih2|w_hh2|gate_w|exp_w] (131 KB)
// ---------------------------------------------------------------------------

typedef __bf16 bf16x8 __attribute__((ext_vector_type(8)));
typedef float floatx4 __attribute__((ext_vector_type(4)));
typedef unsigned short us8 __attribute__((ext_vector_type(8)));

__device__ __forceinline__ unsigned short f2bf(float f){
  union { float f; unsigned u; } c; c.f = f;
  unsigned r = c.u + 0x7FFFu + ((c.u >> 16) & 1u);
  return (unsigned short)(r >> 16);
}
__device__ __forceinline__ float sigm(float x){ return 1.f/(1.f + __expf(-x)); }

__global__ void k_zero(float* __restrict__ p, int n){
  int i = blockIdx.x*blockDim.x + threadIdx.x;
  if (i < n) p[i] = 0.f;
}

// convert the 6 weight tensors fp32 -> bf16 into one packed ws region
// segments: w_ih1 12288 | w_hh1 12288 | w_ih2 12288 | w_hh2 12288 | gate 256 | exp 16384
__global__ void k_cvt(const float* __restrict__ s0, const float* __restrict__ s1,
                      const float* __restrict__ s2, const float* __restrict__ s3,
                      const float* __restrict__ s4, const float* __restrict__ s5,
                      unsigned short* __restrict__ dst){
  int i = blockIdx.x*blockDim.x + threadIdx.x;
  const float* s; int off;
  if      (i < 12288){ s = s0; off = i; }
  else if (i < 24576){ s = s1; off = i - 12288; }
  else if (i < 36864){ s = s2; off = i - 24576; }
  else if (i < 49152){ s = s3; off = i - 36864; }
  else if (i < 49408){ s = s4; off = i - 49152; }
  else if (i < 65792){ s = s5; off = i - 49408; }
  else return;
  dst[i] = f2bf(s[off]);
}

// m[i,d] = src[i,d] + b_edge[d]  (self-loop message: edge_attr==0 -> eemb==bias)
__global__ void k_init_m(const float* __restrict__ src,
                         const float* __restrict__ b_edge,
                         float* __restrict__ m, int total){
  int i = blockIdx.x*blockDim.x + threadIdx.x;
  if (i >= total) return;
  m[i] = src[i] + b_edge[i & 63];
}

// one edge per 64 lanes; lane d handles dim d.
// msg = x[src,d] + b_edge[d] + w_edge[d,:] . ea[e,:]
__global__ void k_edge(const int* __restrict__ ei,
                       const float* __restrict__ ea,
                       const float* __restrict__ x,
                       const float* __restrict__ w_edge,
                       const float* __restrict__ b_edge,
                       float* __restrict__ m, int E){
  long long t = (long long)blockIdx.x*blockDim.x + threadIdx.x;
  int e = (int)(t >> 6);
  if (e >= E) return;
  int d = (int)(t & 63);
  int s   = ei[e];
  int dst = ei[E + e];
  float4 eav = *(const float4*)(ea + (size_t)e*4);
  float4 wv  = *(const float4*)(w_edge + d*4);
  float msg = x[(size_t)s*64 + d] + b_edge[d]
            + eav.x*wv.x + eav.y*wv.y + eav.z*wv.z + eav.w*wv.w;
  atomicAdd(&m[(size_t)dst*64 + d], msg);
}

// GRU cell via MFMA: gi = m @ w_ih^T, gh = x @ w_hh^T, one wave per 16 nodes.
// A layout: A[m=lane&15][k=quad*8+j]; C/D: col=lane&15, row=quad*4+reg (m89/m91).
// out = relu(GRU) fp32.  Layer2 calls with out==x: safe, each wave/lane only
// reads and writes its own addresses, all reads precede the stores in order.
__global__ void __launch_bounds__(256) k_gru(
    const float* __restrict__ m, const float* x,
    const unsigned short* __restrict__ wih, const unsigned short* __restrict__ whh,
    const float* __restrict__ b_ih, const float* __restrict__ b_hh,
    float* out, int tiles, int N){
  int wid = (int)(((long long)blockIdx.x*blockDim.x + threadIdx.x) >> 6);
  if (wid >= tiles) return;
  int lane = threadIdx.x & 63;
  int col = lane & 15, quad = lane >> 4;
  int na = wid*16 + col; if (na > N-1) na = N-1;

  bf16x8 am[2], ax[2];
#pragma unroll
  for (int ks = 0; ks < 2; ++ks){
    int kb = ks*32 + quad*8;
    const float4* mp = (const float4*)(m + (size_t)na*64 + kb);
    float4 lo = mp[0], hi = mp[1];
    us8 tm;
    tm[0]=f2bf(lo.x); tm[1]=f2bf(lo.y); tm[2]=f2bf(lo.z); tm[3]=f2bf(lo.w);
    tm[4]=f2bf(hi.x); tm[5]=f2bf(hi.y); tm[6]=f2bf(hi.z); tm[7]=f2bf(hi.w);
    am[ks] = __builtin_bit_cast(bf16x8, tm);
    const float4* xp = (const float4*)(x + (size_t)na*64 + kb);
    float4 xlo = xp[0], xhi = xp[1];
    us8 tx;
    tx[0]=f2bf(xlo.x); tx[1]=f2bf(xlo.y); tx[2]=f2bf(xlo.z); tx[3]=f2bf(xlo.w);
    tx[4]=f2bf(xhi.x); tx[5]=f2bf(xhi.y); tx[6]=f2bf(xhi.z); tx[7]=f2bf(xhi.w);
    ax[ks] = __builtin_bit_cast(bf16x8, tx);
  }

  floatx4 ai[12], ah[12];
#pragma unroll
  for (int nt = 0; nt < 12; ++nt){ ai[nt] = (floatx4)0.f; ah[nt] = (floatx4)0.f; }
#pragma unroll
  for (int nt = 0; nt < 12; ++nt){
    int r = nt*16 + col;   // output row of w (0..191)
#pragma unroll
    for (int ks = 0; ks < 2; ++ks){
      int kb = ks*32 + quad*8;
      bf16x8 bi = __builtin_bit_cast(bf16x8, *(const us8*)(wih + (size_t)r*64 + kb));
      ai[nt] = __builtin_amdgcn_mfma_f32_16x16x32_bf16(am[ks], bi, ai[nt], 0,0,0);
      bf16x8 bh = __builtin_bit_cast(bf16x8, *(const us8*)(whh + (size_t)r*64 + kb));
      ah[nt] = __builtin_amdgcn_mfma_f32_16x16x32_bf16(ax[ks], bh, ah[nt], 0,0,0);
    }
  }

#pragma unroll
  for (int nt = 0; nt < 4; ++nt){
    int d = nt*16 + col;
    float bir = b_ih[d],      bhr = b_hh[d];
    float biz = b_ih[64+d],   bhz = b_hh[64+d];
    float bin = b_ih[128+d],  bhn = b_hh[128+d];
#pragma unroll
    for (int rg = 0; rg < 4; ++rg){
      int node = wid*16 + quad*4 + rg;
      if (node >= N) continue;
      float rr = sigm(ai[nt  ][rg] + bir + ah[nt  ][rg] + bhr);
      float zz = sigm(ai[nt+4][rg] + biz + ah[nt+4][rg] + bhz);
      float nn = tanhf(ai[nt+8][rg] + bin + rr*(ah[nt+8][rg] + bhn));
      float xv = x[(size_t)node*64 + d];
      float hv = (1.f - zz)*nn + zz*xv;
      out[(size_t)node*64 + d] = fmaxf(hv, 0.f);
    }
  }
}

// MoE: gate logits + 4 experts via MFMA, softmax combine, atomic pool by graph.
__global__ void __launch_bounds__(256) k_moe(
    const float* __restrict__ h,
    const unsigned short* __restrict__ gate_w, const float* __restrict__ gate_b,
    const unsigned short* __restrict__ exp_w,  const float* __restrict__ exp_b,
    const int* __restrict__ batch,
    float* __restrict__ pool, float* __restrict__ cnt, int tiles, int N){
  __shared__ float gsm[4][16][4];
  int gwid = (int)(((long long)blockIdx.x*blockDim.x + threadIdx.x) >> 6);
  int w = threadIdx.x >> 6;
  int lane = threadIdx.x & 63;
  int col = lane & 15, quad = lane >> 4;
  bool active = gwid < tiles;

  floatx4 accg = (floatx4)0.f;
  floatx4 acce[4][4];
#pragma unroll
  for (int e=0;e<4;++e)
#pragma unroll
    for (int nt=0;nt<4;++nt) acce[e][nt] = (floatx4)0.f;

  if (active){
    int na = gwid*16 + col; if (na > N-1) na = N-1;
    bf16x8 a[2];
#pragma unroll
    for (int ks=0; ks<2; ++ks){
      int kb = ks*32 + quad*8;
      const float4* hp = (const float4*)(h + (size_t)na*64 + kb);
      float4 lo = hp[0], hi = hp[1];
      us8 th;
      th[0]=f2bf(lo.x); th[1]=f2bf(lo.y); th[2]=f2bf(lo.z); th[3]=f2bf(lo.w);
      th[4]=f2bf(hi.x); th[5]=f2bf(hi.y); th[6]=f2bf(hi.z); th[7]=f2bf(hi.w);
      a[ks] = __builtin_bit_cast(bf16x8, th);
      us8 braw = {0,0,0,0,0,0,0,0};
      if (col < 4) braw = *(const us8*)(gate_w + col*64 + kb);
      accg = __builtin_amdgcn_mfma_f32_16x16x32_bf16(a[ks], __builtin_bit_cast(bf16x8, braw), accg, 0,0,0);
    }
#pragma unroll
    for (int e=0;e<4;++e)
#pragma unroll
      for (int nt=0;nt<4;++nt)
#pragma unroll
        for (int ks=0;ks<2;++ks){
          int kb = ks*32 + quad*8;
          bf16x8 b = __builtin_bit_cast(bf16x8,
              *(const us8*)(exp_w + ((size_t)e*64 + nt*16 + col)*64 + kb));
          acce[e][nt] = __builtin_amdgcn_mfma_f32_16x16x32_bf16(a[ks], b, acce[e][nt], 0,0,0);
        }
    if (col < 4){
      float gb = gate_b[col];
#pragma unroll
      for (int rg=0;rg<4;++rg) gsm[w][quad*4+rg][col] = accg[rg] + gb;
    }
  }
  __syncthreads();
  if (!active) return;

#pragma unroll
  for (int rg=0; rg<4; ++rg){
    int nrow = quad*4 + rg;
    int node = gwid*16 + nrow;
    if (node >= N) continue;
    float g0=gsm[w][nrow][0], g1=gsm[w][nrow][1], g2=gsm[w][nrow][2], g3=gsm[w][nrow][3];
    float mx = fmaxf(fmaxf(g0,g1), fmaxf(g2,g3));
    float e0=__expf(g0-mx), e1=__expf(g1-mx), e2=__expf(g2-mx), e3=__expf(g3-mx);
    float inv = 1.f/(e0+e1+e2+e3);
    float w0=e0*inv, w1=e1*inv, w2=e2*inv, w3=e3*inv;
    int b = batch[node];
#pragma unroll
    for (int nt=0;nt<4;++nt){
      int o = nt*16 + col;
      float v = w0*fmaxf(acce[0][nt][rg] + exp_b[      o], 0.f)
              + w1*fmaxf(acce[1][nt][rg] + exp_b[ 64 + o], 0.f)
              + w2*fmaxf(acce[2][nt][rg] + exp_b[128 + o], 0.f)
              + w3*fmaxf(acce[3][nt][rg] + exp_b[192 + o], 0.f);
      atomicAdd(&pool[b*64 + o], v);
    }
    if (col == 0) atomicAdd(&cnt[b], 1.f);
  }
}

// graph_emb = pool/cnt; out = [emb, emb, logits];  logits = [flag|emb] @ fc_w^T + fc_b
__global__ void k_head(const float* __restrict__ pool, const float* __restrict__ cnt,
                       const float* __restrict__ ldxb,
                       const float* __restrict__ proj_w, const float* __restrict__ proj_b,
                       const float* __restrict__ fc_w, const float* __restrict__ fc_b,
                       float* __restrict__ out, int B){
  __shared__ float ges[64];
  int b = blockIdx.x, t = threadIdx.x;
  float denom = fmaxf(cnt[b], 1.f);
  float ge = pool[b*64 + t] / denom;
  out[(size_t)b*64 + t]                = ge;
  out[(size_t)B*64 + (size_t)b*64 + t] = ge;
  ges[t] = ge;
  __syncthreads();
  if (t < 10){
    float acc = fc_b[t];
    float fl = ldxb[b];
    const float* fr = fc_w + t*164;
    for (int p=0;p<100;++p) acc += (fl*proj_w[p] + proj_b[p]) * fr[p];
    for (int d=0; d<64; ++d) acc += ges[d]*fr[100+d];
    out[(size_t)B*128 + (size_t)b*10 + t] = acc;
  }
}

extern "C" void kernel_launch(void* const* d_in, const int* in_sizes, int n_in,
                              void* d_out, int out_size, void* d_ws, size_t ws_size,
                              hipStream_t stream){
  const float* x      = (const float*)d_in[0];
  const int*   ei     = (const int*)d_in[1];
  const float* ea     = (const float*)d_in[2];
  const int*   batch  = (const int*)d_in[3];
  const float* ldxb   = (const float*)d_in[4];
  const float* w_edge1= (const float*)d_in[5];
  const float* b_edge1= (const float*)d_in[6];
  const float* w_ih1  = (const float*)d_in[7];
  const float* w_hh1  = (const float*)d_in[8];
  const float* b_ih1  = (const float*)d_in[9];
  const float* b_hh1  = (const float*)d_in[10];
  const float* w_edge2= (const float*)d_in[11];
  const float* b_edge2= (const float*)d_in[12];
  const float* w_ih2  = (const float*)d_in[13];
  const float* w_hh2  = (const float*)d_in[14];
  const float* b_ih2  = (const float*)d_in[15];
  const float* b_hh2  = (const float*)d_in[16];
  const float* gate_w = (const float*)d_in[17];
  const float* gate_b = (const float*)d_in[18];
  const float* exp_w  = (const float*)d_in[19];
  const float* exp_b  = (const float*)d_in[20];
  const float* proj_w = (const float*)d_in[21];
  const float* proj_b = (const float*)d_in[22];
  const float* fc_w   = (const float*)d_in[23];
  const float* fc_b   = (const float*)d_in[24];
  float* out = (float*)d_out;

  int N = in_sizes[0] / 64;
  int E = in_sizes[1] / 2;
  int B = in_sizes[4];
  int tiles = (N + 15) / 16;
  int nTot = N * 64;

  float* m    = (float*)d_ws;
  float* h    = m + (size_t)nTot;
  float* pool = h + (size_t)nTot;
  float* cnt  = pool + (size_t)B*64;
  unsigned short* wbf = (unsigned short*)(cnt + B);
  unsigned short* wih1bf = wbf;
  unsigned short* whh1bf = wbf + 12288;
  unsigned short* wih2bf = wbf + 24576;
  unsigned short* whh2bf = wbf + 36864;
  unsigned short* gatebf = wbf + 49152;
  unsigned short* expbf  = wbf + 49408;

  dim3 blk(256);
  int edgeBlocks = (int)(((long long)E*64 + 255)/256);
  int nodeBlocks = (nTot + 255)/256;
  int waveBlocks = (tiles + 3)/4;

  k_cvt<<<(65792 + 255)/256, blk, 0, stream>>>(w_ih1, w_hh1, w_ih2, w_hh2, gate_w, exp_w, wbf);
  k_zero<<<(B*65 + 255)/256, blk, 0, stream>>>(pool, B*65);
  // layer 1
  k_init_m<<<nodeBlocks, blk, 0, stream>>>(x, b_edge1, m, nTot);
  k_edge<<<edgeBlocks, blk, 0, stream>>>(ei, ea, x, w_edge1, b_edge1, m, E);
  k_gru<<<waveBlocks, blk, 0, stream>>>(m, x, wih1bf, whh1bf, b_ih1, b_hh1, h, tiles, N);
  // layer 2 (in-place h update; see aliasing note in k_gru)
  k_init_m<<<nodeBlocks, blk, 0, stream>>>(h, b_edge2, m, nTot);
  k_edge<<<edgeBlocks, blk, 0, stream>>>(ei, ea, h, w_edge2, b_edge2, m, E);
  k_gru<<<waveBlocks, blk, 0, stream>>>(m, h, wih2bf, whh2bf, b_ih2, b_hh2, h, tiles, N);
  // MoE + segment pool
  k_moe<<<waveBlocks, blk, 0, stream>>>(h, gatebf, gate_b, expbf, exp_b, batch, pool, cnt, tiles, N);
  // heads
  k_head<<<B, 64, 0, stream>>>(pool, cnt, ldxb, proj_w, proj_b, fc_w, fc_b, out, B);
}

// Round 3
// 629.301 us; speedup vs baseline: 1.4210x; 1.4210x over previous
//
#include <hip/hip_runtime.h>
#include <stdint.h>

// ---------------------------------------------------------------------------
// GNNWithMoE: 2x GGNN(edge-embed + scatter-add + GRU) -> soft MoE -> mean pool
// ALL float tensors are fp32; ints int32; out fp32.
// MFMA GEMMs run in bf16 (inputs converted in-kernel, weights pre-converted).
// Workspace layout (d_ws):
//   m    : N*64 fp32 message accumulator (12.8 MB); reused as MoE output v
//   h    : N*64 fp32 hidden             (12.8 MB)
//   wbf  : bf16 weights [w_ih1|w_hh1|w_ih2|w_hh2|gate_w|exp_w] (131 KB)
// Pooling: batch is sorted -> segmented mean with one block per graph
// (binary search for boundaries), NO global atomics (round2 showed 331us of
// same-address atomic serialization in k_moe's pool/cnt atomics).
// ---------------------------------------------------------------------------

typedef __bf16 bf16x8 __attribute__((ext_vector_type(8)));
typedef float floatx4 __attribute__((ext_vector_type(4)));
typedef unsigned short us8 __attribute__((ext_vector_type(8)));

__device__ __forceinline__ unsigned short f2bf(float f){
  union { float f; unsigned u; } c; c.f = f;
  unsigned r = c.u + 0x7FFFu + ((c.u >> 16) & 1u);
  return (unsigned short)(r >> 16);
}
__device__ __forceinline__ float sigm(float x){ return 1.f/(1.f + __expf(-x)); }

// convert the 6 weight tensors fp32 -> bf16 into one packed ws region
__global__ void k_cvt(const float* __restrict__ s0, const float* __restrict__ s1,
                      const float* __restrict__ s2, const float* __restrict__ s3,
                      const float* __restrict__ s4, const float* __restrict__ s5,
                      unsigned short* __restrict__ dst){
  int i = blockIdx.x*blockDim.x + threadIdx.x;
  const float* s; int off;
  if      (i < 12288){ s = s0; off = i; }
  else if (i < 24576){ s = s1; off = i - 12288; }
  else if (i < 36864){ s = s2; off = i - 24576; }
  else if (i < 49152){ s = s3; off = i - 36864; }
  else if (i < 49408){ s = s4; off = i - 49152; }
  else if (i < 65792){ s = s5; off = i - 49408; }
  else return;
  dst[i] = f2bf(s[off]);
}

// m[i,d] = src[i,d] + b_edge[d]  (self-loop message: edge_attr==0 -> eemb==bias)
__global__ void k_init_m(const float* __restrict__ src,
                         const float* __restrict__ b_edge,
                         float* __restrict__ m, int total){
  int i = blockIdx.x*blockDim.x + threadIdx.x;
  if (i >= total) return;
  m[i] = src[i] + b_edge[i & 63];
}

// one edge per 64 lanes; lane d handles dim d.
// msg = x[src,d] + b_edge[d] + w_edge[d,:] . ea[e,:]
__global__ void k_edge(const int* __restrict__ ei,
                       const float* __restrict__ ea,
                       const float* __restrict__ x,
                       const float* __restrict__ w_edge,
                       const float* __restrict__ b_edge,
                       float* __restrict__ m, int E){
  long long t = (long long)blockIdx.x*blockDim.x + threadIdx.x;
  int e = (int)(t >> 6);
  if (e >= E) return;
  int d = (int)(t & 63);
  int s   = ei[e];
  int dst = ei[E + e];
  float4 eav = *(const float4*)(ea + (size_t)e*4);
  float4 wv  = *(const float4*)(w_edge + d*4);
  float msg = x[(size_t)s*64 + d] + b_edge[d]
            + eav.x*wv.x + eav.y*wv.y + eav.z*wv.z + eav.w*wv.w;
  atomicAdd(&m[(size_t)dst*64 + d], msg);
}

// GRU cell via MFMA: gi = m @ w_ih^T, gh = x @ w_hh^T, one wave per 16 nodes.
// A layout: A[m=lane&15][k=quad*8+j]; C/D: col=lane&15, row=quad*4+reg (m89/m91).
__global__ void __launch_bounds__(256) k_gru(
    const float* __restrict__ m, const float* x,
    const unsigned short* __restrict__ wih, const unsigned short* __restrict__ whh,
    const float* __restrict__ b_ih, const float* __restrict__ b_hh,
    float* out, int tiles, int N){
  int wid = (int)(((long long)blockIdx.x*blockDim.x + threadIdx.x) >> 6);
  if (wid >= tiles) return;
  int lane = threadIdx.x & 63;
  int col = lane & 15, quad = lane >> 4;
  int na = wid*16 + col; if (na > N-1) na = N-1;

  bf16x8 am[2], ax[2];
#pragma unroll
  for (int ks = 0; ks < 2; ++ks){
    int kb = ks*32 + quad*8;
    const float4* mp = (const float4*)(m + (size_t)na*64 + kb);
    float4 lo = mp[0], hi = mp[1];
    us8 tm;
    tm[0]=f2bf(lo.x); tm[1]=f2bf(lo.y); tm[2]=f2bf(lo.z); tm[3]=f2bf(lo.w);
    tm[4]=f2bf(hi.x); tm[5]=f2bf(hi.y); tm[6]=f2bf(hi.z); tm[7]=f2bf(hi.w);
    am[ks] = __builtin_bit_cast(bf16x8, tm);
    const float4* xp = (const float4*)(x + (size_t)na*64 + kb);
    float4 xlo = xp[0], xhi = xp[1];
    us8 tx;
    tx[0]=f2bf(xlo.x); tx[1]=f2bf(xlo.y); tx[2]=f2bf(xlo.z); tx[3]=f2bf(xlo.w);
    tx[4]=f2bf(xhi.x); tx[5]=f2bf(xhi.y); tx[6]=f2bf(xhi.z); tx[7]=f2bf(xhi.w);
    ax[ks] = __builtin_bit_cast(bf16x8, tx);
  }

  floatx4 ai[12], ah[12];
#pragma unroll
  for (int nt = 0; nt < 12; ++nt){ ai[nt] = (floatx4)0.f; ah[nt] = (floatx4)0.f; }
#pragma unroll
  for (int nt = 0; nt < 12; ++nt){
    int r = nt*16 + col;   // output row of w (0..191)
#pragma unroll
    for (int ks = 0; ks < 2; ++ks){
      int kb = ks*32 + quad*8;
      bf16x8 bi = __builtin_bit_cast(bf16x8, *(const us8*)(wih + (size_t)r*64 + kb));
      ai[nt] = __builtin_amdgcn_mfma_f32_16x16x32_bf16(am[ks], bi, ai[nt], 0,0,0);
      bf16x8 bh = __builtin_bit_cast(bf16x8, *(const us8*)(whh + (size_t)r*64 + kb));
      ah[nt] = __builtin_amdgcn_mfma_f32_16x16x32_bf16(ax[ks], bh, ah[nt], 0,0,0);
    }
  }

#pragma unroll
  for (int nt = 0; nt < 4; ++nt){
    int d = nt*16 + col;
    float bir = b_ih[d],      bhr = b_hh[d];
    float biz = b_ih[64+d],   bhz = b_hh[64+d];
    float bin = b_ih[128+d],  bhn = b_hh[128+d];
#pragma unroll
    for (int rg = 0; rg < 4; ++rg){
      int node = wid*16 + quad*4 + rg;
      if (node >= N) continue;
      float rr = sigm(ai[nt  ][rg] + bir + ah[nt  ][rg] + bhr);
      float zz = sigm(ai[nt+4][rg] + biz + ah[nt+4][rg] + bhz);
      float nn = tanhf(ai[nt+8][rg] + bin + rr*(ah[nt+8][rg] + bhn));
      float xv = x[(size_t)node*64 + d];
      float hv = (1.f - zz)*nn + zz*xv;
      out[(size_t)node*64 + d] = fmaxf(hv, 0.f);
    }
  }
}

// MoE: gate logits + 4 experts via MFMA, softmax combine -> v[node][64] stores.
__global__ void __launch_bounds__(256) k_moe(
    const float* __restrict__ h,
    const unsigned short* __restrict__ gate_w, const float* __restrict__ gate_b,
    const unsigned short* __restrict__ exp_w,  const float* __restrict__ exp_b,
    float* __restrict__ v_out, int tiles, int N){
  __shared__ float gsm[4][16][4];
  int gwid = (int)(((long long)blockIdx.x*blockDim.x + threadIdx.x) >> 6);
  int w = threadIdx.x >> 6;
  int lane = threadIdx.x & 63;
  int col = lane & 15, quad = lane >> 4;
  bool active = gwid < tiles;

  floatx4 accg = (floatx4)0.f;
  floatx4 acce[4][4];
#pragma unroll
  for (int e=0;e<4;++e)
#pragma unroll
    for (int nt=0;nt<4;++nt) acce[e][nt] = (floatx4)0.f;

  if (active){
    int na = gwid*16 + col; if (na > N-1) na = N-1;
    bf16x8 a[2];
#pragma unroll
    for (int ks=0; ks<2; ++ks){
      int kb = ks*32 + quad*8;
      const float4* hp = (const float4*)(h + (size_t)na*64 + kb);
      float4 lo = hp[0], hi = hp[1];
      us8 th;
      th[0]=f2bf(lo.x); th[1]=f2bf(lo.y); th[2]=f2bf(lo.z); th[3]=f2bf(lo.w);
      th[4]=f2bf(hi.x); th[5]=f2bf(hi.y); th[6]=f2bf(hi.z); th[7]=f2bf(hi.w);
      a[ks] = __builtin_bit_cast(bf16x8, th);
      us8 braw = {0,0,0,0,0,0,0,0};
      if (col < 4) braw = *(const us8*)(gate_w + col*64 + kb);
      accg = __builtin_amdgcn_mfma_f32_16x16x32_bf16(a[ks], __builtin_bit_cast(bf16x8, braw), accg, 0,0,0);
    }
#pragma unroll
    for (int e=0;e<4;++e)
#pragma unroll
      for (int nt=0;nt<4;++nt)
#pragma unroll
        for (int ks=0;ks<2;++ks){
          int kb = ks*32 + quad*8;
          bf16x8 b = __builtin_bit_cast(bf16x8,
              *(const us8*)(exp_w + ((size_t)e*64 + nt*16 + col)*64 + kb));
          acce[e][nt] = __builtin_amdgcn_mfma_f32_16x16x32_bf16(a[ks], b, acce[e][nt], 0,0,0);
        }
    if (col < 4){
      float gb = gate_b[col];
#pragma unroll
      for (int rg=0;rg<4;++rg) gsm[w][quad*4+rg][col] = accg[rg] + gb;
    }
  }
  __syncthreads();
  if (!active) return;

#pragma unroll
  for (int rg=0; rg<4; ++rg){
    int nrow = quad*4 + rg;
    int node = gwid*16 + nrow;
    if (node >= N) continue;
    float g0=gsm[w][nrow][0], g1=gsm[w][nrow][1], g2=gsm[w][nrow][2], g3=gsm[w][nrow][3];
    float mx = fmaxf(fmaxf(g0,g1), fmaxf(g2,g3));
    float e0=__expf(g0-mx), e1=__expf(g1-mx), e2=__expf(g2-mx), e3=__expf(g3-mx);
    float inv = 1.f/(e0+e1+e2+e3);
    float w0=e0*inv, w1=e1*inv, w2=e2*inv, w3=e3*inv;
#pragma unroll
    for (int nt=0;nt<4;++nt){
      int o = nt*16 + col;
      float v = w0*fmaxf(acce[0][nt][rg] + exp_b[      o], 0.f)
              + w1*fmaxf(acce[1][nt][rg] + exp_b[ 64 + o], 0.f)
              + w2*fmaxf(acce[2][nt][rg] + exp_b[128 + o], 0.f)
              + w3*fmaxf(acce[3][nt][rg] + exp_b[192 + o], 0.f);
      v_out[(size_t)node*64 + o] = v;
    }
  }
}

__device__ __forceinline__ int lower_bound_i(const int* __restrict__ a, int n, int key){
  int lo = 0, hi = n;
  while (lo < hi){ int mid = (lo + hi) >> 1; if (a[mid] < key) lo = mid + 1; else hi = mid; }
  return lo;
}

// One block per graph: segmented mean over sorted batch (no atomics) + heads.
// out = [emb, emb, logits]; logits = [flag|emb] @ fc_w^T + fc_b
__global__ void __launch_bounds__(256) k_pool_head(
    const float* __restrict__ v, const int* __restrict__ batch, int N, int B,
    const float* __restrict__ ldxb,
    const float* __restrict__ proj_w, const float* __restrict__ proj_b,
    const float* __restrict__ fc_w, const float* __restrict__ fc_b,
    float* __restrict__ out){
  __shared__ float red[4][64];
  __shared__ float ges[64];
  int b = blockIdx.x, t = threadIdx.x;
  int d = t & 63, r = t >> 6;
  int start = lower_bound_i(batch, N, b);
  int end   = lower_bound_i(batch, N, b + 1);
  float acc = 0.f;
  for (int i = start + r; i < end; i += 4)
    acc += v[(size_t)i*64 + d];
  red[r][d] = acc;
  __syncthreads();
  if (r == 0){
    float cntf = (float)(end - start);
    float ge = (red[0][d] + red[1][d] + red[2][d] + red[3][d]) / fmaxf(cntf, 1.f);
    ges[d] = ge;
    out[(size_t)b*64 + d]                = ge;
    out[(size_t)B*64 + (size_t)b*64 + d] = ge;
  }
  __syncthreads();
  if (t < 10){
    float acc2 = fc_b[t];
    float fl = ldxb[b];
    const float* fr = fc_w + t*164;
    for (int p = 0; p < 100; ++p) acc2 += (fl*proj_w[p] + proj_b[p]) * fr[p];
    for (int dd = 0; dd < 64; ++dd) acc2 += ges[dd]*fr[100 + dd];
    out[(size_t)B*128 + (size_t)b*10 + t] = acc2;
  }
}

extern "C" void kernel_launch(void* const* d_in, const int* in_sizes, int n_in,
                              void* d_out, int out_size, void* d_ws, size_t ws_size,
                              hipStream_t stream){
  const float* x      = (const float*)d_in[0];
  const int*   ei     = (const int*)d_in[1];
  const float* ea     = (const float*)d_in[2];
  const int*   batch  = (const int*)d_in[3];
  const float* ldxb   = (const float*)d_in[4];
  const float* w_edge1= (const float*)d_in[5];
  const float* b_edge1= (const float*)d_in[6];
  const float* w_ih1  = (const float*)d_in[7];
  const float* w_hh1  = (const float*)d_in[8];
  const float* b_ih1  = (const float*)d_in[9];
  const float* b_hh1  = (const float*)d_in[10];
  const float* w_edge2= (const float*)d_in[11];
  const float* b_edge2= (const float*)d_in[12];
  const float* w_ih2  = (const float*)d_in[13];
  const float* w_hh2  = (const float*)d_in[14];
  const float* b_ih2  = (const float*)d_in[15];
  const float* b_hh2  = (const float*)d_in[16];
  const float* gate_w = (const float*)d_in[17];
  const float* gate_b = (const float*)d_in[18];
  const float* exp_w  = (const float*)d_in[19];
  const float* exp_b  = (const float*)d_in[20];
  const float* proj_w = (const float*)d_in[21];
  const float* proj_b = (const float*)d_in[22];
  const float* fc_w   = (const float*)d_in[23];
  const float* fc_b   = (const float*)d_in[24];
  float* out = (float*)d_out;

  int N = in_sizes[0] / 64;
  int E = in_sizes[1] / 2;
  int B = in_sizes[4];
  int tiles = (N + 15) / 16;
  int nTot = N * 64;

  float* m    = (float*)d_ws;           // also reused as MoE output v
  float* h    = m + (size_t)nTot;
  unsigned short* wbf = (unsigned short*)(h + (size_t)nTot);
  unsigned short* wih1bf = wbf;
  unsigned short* whh1bf = wbf + 12288;
  unsigned short* wih2bf = wbf + 24576;
  unsigned short* whh2bf = wbf + 36864;
  unsigned short* gatebf = wbf + 49152;
  unsigned short* expbf  = wbf + 49408;

  dim3 blk(256);
  int edgeBlocks = (int)(((long long)E*64 + 255)/256);
  int nodeBlocks = (nTot + 255)/256;
  int waveBlocks = (tiles + 3)/4;

  k_cvt<<<(65792 + 255)/256, blk, 0, stream>>>(w_ih1, w_hh1, w_ih2, w_hh2, gate_w, exp_w, wbf);
  // layer 1
  k_init_m<<<nodeBlocks, blk, 0, stream>>>(x, b_edge1, m, nTot);
  k_edge<<<edgeBlocks, blk, 0, stream>>>(ei, ea, x, w_edge1, b_edge1, m, E);
  k_gru<<<waveBlocks, blk, 0, stream>>>(m, x, wih1bf, whh1bf, b_ih1, b_hh1, h, tiles, N);
  // layer 2 (in-place h update; see aliasing note in k_gru)
  k_init_m<<<nodeBlocks, blk, 0, stream>>>(h, b_edge2, m, nTot);
  k_edge<<<edgeBlocks, blk, 0, stream>>>(ei, ea, h, w_edge2, b_edge2, m, E);
  k_gru<<<waveBlocks, blk, 0, stream>>>(m, h, wih2bf, whh2bf, b_ih2, b_hh2, h, tiles, N);
  // MoE -> v (reuse m), then segmented-mean pool + heads (no atomics)
  k_moe<<<waveBlocks, blk, 0, stream>>>(h, gatebf, gate_b, expbf, exp_b, m, tiles, N);
  k_pool_head<<<B, blk, 0, stream>>>(m, batch, N, B, ldxb, proj_w, proj_b, fc_w, fc_b, out);
}